// Round 5
// baseline (23794.928 us; speedup 1.0000x reference)
//
#include <hip/hip_runtime.h>
#include <stdint.h>

// B=32, T=128, DIN=DOUT=1024. Input dtypes detected at runtime (bf16 vs fp32).
typedef unsigned short u16;
typedef __attribute__((ext_vector_type(8))) short short8;   // 8 x bf16 MFMA operand
typedef __attribute__((ext_vector_type(4))) float f32x4;    // MFMA accumulator

// ---- workspace layout (bytes) ----
#define LEAF_OFF   0                          // 16 leaf counters x 256 B
#define FLAG_OFF   4096                       // epoch flag (own line)
#define FLG_OFF    4352                       // 13 dtype flags
#define HBF_OFF    8192                       // h bf16: 64 KB (must start zeroed)
#define ZERO_BYTES (HBF_OFF + 32*1024*2)
#define RH_OFF     ZERO_BYTES                 // r*h bf16: 64 KB (write-before-read)
#define BS_OFF     (RH_OFF + 32*1024*2)       // bias sums fp32: 3*1024*4
#define XB_OFF     (1<<20)                    // x bf16: 8 MB
#define WB_OFF     (9<<20)                    // 6 weight mats bf16: 12 MB
#define WS_FULL    (21u<<20)

__device__ __forceinline__ float bf2f(u16 v) {
    unsigned u = ((unsigned)v) << 16;
    return __builtin_bit_cast(float, u);
}
__device__ __forceinline__ u16 f2bf(float f) {
    unsigned u = __builtin_bit_cast(unsigned, f);
    unsigned r = 0x7fffu + ((u >> 16) & 1u);   // RNE
    return (u16)((u + r) >> 16);
}
__device__ __forceinline__ float sigm(float x) { return 1.0f / (1.0f + __expf(-x)); }

__device__ __forceinline__ short8 cvt8f(const float* f) {
    short8 r;
#pragma unroll
    for (int j = 0; j < 8; j++) r[j] = (short)f2bf(f[j]);
    return r;
}
__device__ __forceinline__ short8 cvt8any(const void* src, long ei, unsigned isbf) {
    if (isbf) return *(const short8*)((const u16*)src + ei);
    return cvt8f((const float*)src + ei);
}

// ---- two-level grid barrier (decontended) ----
// Arrivals: atomicAdd on leaf[blk&15] (16 lines, 256 B apart) -> ~8 RMWs/line.
// Block 0 leader sweeps leaves until sum == nb*(e+1) (monotone, no reset),
// then release-stores epoch flag. All other leaders poll the flag READ-ONLY.
__device__ __forceinline__ void gbar2(unsigned* leafs, unsigned* flag,
                                      unsigned e, int blk, unsigned nb) {
    __threadfence();                 // release this block's global writes
    __syncthreads();
    if (threadIdx.x == 0) {
        __hip_atomic_fetch_add(&leafs[(blk & 15) * 64], 1u,
                               __ATOMIC_RELEASE, __HIP_MEMORY_SCOPE_AGENT);
        if (blk == 0) {
            const unsigned target = nb * (e + 1);
            for (;;) {
                unsigned s = 0;
#pragma unroll
                for (int i = 0; i < 16; i++)
                    s += __hip_atomic_load(&leafs[i * 64], __ATOMIC_ACQUIRE,
                                           __HIP_MEMORY_SCOPE_AGENT);
                if (s >= target) break;
                __builtin_amdgcn_s_sleep(1);
            }
            __hip_atomic_store(flag, e + 1, __ATOMIC_RELEASE,
                               __HIP_MEMORY_SCOPE_AGENT);
        } else {
            while (__hip_atomic_load(flag, __ATOMIC_ACQUIRE,
                                     __HIP_MEMORY_SCOPE_AGENT) < e + 1)
                __builtin_amdgcn_s_sleep(1);
        }
    }
    __syncthreads();
    __threadfence();                 // acquire side for all threads
}

struct Ptrs { const void* p[13]; };

// dtype detector: bf16 u16s have exponent in [100,140] (or zero) ~100% of the
// time for N(0,s) data; fp32 read as u16 passes ~58%.
__global__ __launch_bounds__(256) void detect_k(Ptrs ps, unsigned* flags) {
    const u16* a = (const u16*)ps.p[blockIdx.x];
    __shared__ int tot;
    if (threadIdx.x == 0) tot = 0;
    __syncthreads();
    int cnt = 0;
    for (int i = threadIdx.x; i < 1024; i += 256) {
        unsigned u = a[i];
        unsigned e = (u >> 7) & 0xFF;
        cnt += (e == 0 || (e >= 100 && e <= 140)) ? 1 : 0;
    }
    atomicAdd(&tot, cnt);
    __syncthreads();
    if (threadIdx.x == 0) flags[blockIdx.x] = (tot >= 920) ? 1u : 0u;
}

struct SPtrs { const void* x; const void* W[6]; const void* b[6]; };
// W order: Wz,Uz,Wr,Ur,Wh,Uh (flags 1,3,5,7,9,11); b pairs (bz,cz),(br,cr),(bh,ch).

__global__ __launch_bounds__(256) void stage_k(SPtrs ps, const unsigned* __restrict__ flags,
                                               u16* __restrict__ xb, u16* __restrict__ wb,
                                               float* __restrict__ bs, int do_x) {
    int blk = blockIdx.x, tid = threadIdx.x;
    int xblocks = do_x ? 2048 : 0;
    if (blk < xblocks) {                         // x: 4M elems
        long ei = ((long)blk * 256 + tid) * 8;
        *(short8*)(xb + ei) = cvt8any(ps.x, ei, flags[0]);
    } else if (blk < xblocks + 6 * 512) {        // weights: 1M elems each
        int r = (blk - xblocks) >> 9;
        const int fidx[6] = {1, 3, 5, 7, 9, 11};
        long ei = ((long)((blk - xblocks) & 511) * 256 + tid) * 8;
        *(short8*)(wb + (long)r * 1048576 + ei) = cvt8any(ps.W[r], ei, flags[fidx[r]]);
    } else {                                     // bias sums: bs[0]=z, [1]=r, [2]=h
        const int fb[3] = {2, 6, 10}, fc[3] = {4, 8, 12};
        for (int g = 0; g < 3; g++)
            for (int i = tid; i < 1024; i += 256) {
                float b = flags[fb[g]] ? bf2f(((const u16*)ps.b[2 * g])[i])
                                       : ((const float*)ps.b[2 * g])[i];
                float c = flags[fc[g]] ? bf2f(((const u16*)ps.b[2 * g + 1])[i])
                                       : ((const float*)ps.b[2 * g + 1])[i];
                bs[g * 1024 + i] = b + c;
            }
    }
}

// ---- persistent GRU: 128 blocks x 1024 thr (16 waves), K-split chains ----
// Block (ct=blk>>1, rt=blk&1) owns rows R=[16rt,+16) (batch), cols C=[16ct,+16).
// Phase A (16 waves, 8 MFMAs each): hUr x4, xWr x4, hUz x4, xWz x4 (K-quarters);
//   LDS-reduce -> wave0 publishes rh (global), wave1 keeps z in LDS.
// Phase B (16 waves, 4 MFMAs each): rh@Uh x8 + x@Wh x8 (K-eighths);
//   LDS-reduce -> wave0 updates h, publishes hbf + out.
__global__ __launch_bounds__(1024, 4) void gru_rec(
    const void* __restrict__ xbase, int xmode,   // 1: xbase bf16-staged; 0: raw x
    const u16* __restrict__ wb, const float* __restrict__ bs,
    u16* __restrict__ hbf, u16* __restrict__ rhbuf,
    const unsigned* __restrict__ flags,
    unsigned* __restrict__ leafs, unsigned* __restrict__ gflag,
    void* __restrict__ out)
{
    const int tid  = threadIdx.x;
    const int lane = tid & 63, wave = tid >> 6;      // wave 0..15
    const int quad = lane >> 4, ln = lane & 15;
    const int blk  = blockIdx.x;
    const unsigned NB = gridDim.x;

    const unsigned xisbf = xmode ? 1u : flags[0];
    const unsigned outbf = flags[0];

    const int ct = blk >> 1, rt = blk & 1;
    const int R = rt * 16, C0 = ct * 16;

    // Phase A role: g = wave>>2 (0:hUr 1:xWr 2:hUz 3:xWz), kq = wave&3.
    const int gA  = wave >> 2, kqA = wave & 3;
    const int kb0 = kqA * 256;
    const int wmapA[4] = {3, 2, 1, 0};               // -> Ur, Wr, Uz, Wz
    const u16* BwA = wb + (long)wmapA[gA] * 1048576 + (C0 + ln) * 1024 + kb0 + quad * 8;
    const bool hA  = (gA == 0) || (gA == 2);
    const u16* hAp = hbf + (R + ln) * 1024 + kb0 + quad * 8;
    const long xAo = ((long)(R + ln) * 128) * 1024 + kb0 + quad * 8;  // + t*1024

    // Phase B role: gB = wave>>3 (0:rh@Uh 1:x@Wh), ke = wave&7.
    const int gB  = wave >> 3, keB = wave & 7;
    const int kb1 = keB * 128;
    const u16* BwB = wb + (long)(gB ? 4 : 5) * 1048576 + (C0 + ln) * 1024 + kb1 + quad * 8;
    const u16* rhp = rhbuf + (R + ln) * 1024 + kb1 + quad * 8;
    const long xBo = ((long)(R + ln) * 128) * 1024 + kb1 + quad * 8;  // + t*1024

    const float bias_z = bs[C0 + ln];
    const float bias_r = bs[1024 + C0 + ln];
    const float bias_h = bs[2048 + C0 + ln];

    __shared__ float sA[16][64][4];    // per-wave partials (reused phase B)
    __shared__ float zt[64][4];        // z tile (row quad*4+r, col ln)
    __shared__ float ht[64][4];        // h fp32 tile (block-private)

    if (wave == 0)
#pragma unroll
        for (int r = 0; r < 4; r++) ht[lane][r] = 0.f;
    __syncthreads();

    for (int t = 0; t < 128; t++) {
        { // ---- phase A chains: 8 MFMAs ----
            f32x4 acc = (f32x4){0.f, 0.f, 0.f, 0.f};
            const long xo = xAo + (long)t * 1024;
#pragma unroll
            for (int i = 0; i < 8; i++) {
                const int k = i * 32;
                short8 a = hA ? *(const short8*)(hAp + k)
                              : cvt8any(xbase, xo + k, xisbf);
                acc = __builtin_amdgcn_mfma_f32_16x16x32_bf16(
                    a, *(const short8*)(BwA + k), acc, 0, 0, 0);
            }
#pragma unroll
            for (int r = 0; r < 4; r++) sA[wave][lane][r] = acc[r];
        }
        __syncthreads();
        if (wave == 0) {        // r -> rh publish (uses h_{t-1} from ht)
#pragma unroll
            for (int r = 0; r < 4; r++) {
                float s = bias_r;
#pragma unroll
                for (int w = 0; w < 8; w++) s += sA[w][lane][r];
                float rv = sigm(s);
                float rh = rv * ht[lane][r];
                rhbuf[(R + quad * 4 + r) * 1024 + C0 + ln] = f2bf(rh);
            }
        } else if (wave == 1) { // z -> LDS
#pragma unroll
            for (int r = 0; r < 4; r++) {
                float s = bias_z;
#pragma unroll
                for (int w = 8; w < 16; w++) s += sA[w][lane][r];
                zt[lane][r] = sigm(s);
            }
        }
        gbar2(leafs, gflag, 2 * t, blk, NB);
        { // ---- phase B chains: 4 MFMAs ----
            f32x4 acc = (f32x4){0.f, 0.f, 0.f, 0.f};
            const long xo = xBo + (long)t * 1024;
#pragma unroll
            for (int i = 0; i < 4; i++) {
                const int k = i * 32;
                short8 a = (gB == 0) ? *(const short8*)(rhp + k)
                                     : cvt8any(xbase, xo + k, xisbf);
                acc = __builtin_amdgcn_mfma_f32_16x16x32_bf16(
                    a, *(const short8*)(BwB + k), acc, 0, 0, 0);
            }
#pragma unroll
            for (int r = 0; r < 4; r++) sA[wave][lane][r] = acc[r];
        }
        __syncthreads();
        if (wave == 0) {        // combine: h' = (1-z)h + z*sigm(.)
#pragma unroll
            for (int r = 0; r < 4; r++) {
                float s = bias_h;
#pragma unroll
                for (int w = 0; w < 16; w++) s += sA[w][lane][r];
                float hh = sigm(s);
                float z  = zt[lane][r];
                float hv = ht[lane][r];
                float hn = (1.0f - z) * hv + z * hh;
                ht[lane][r] = hn;
                u16 hb = f2bf(hn);
                int row = quad * 4 + r;
                hbf[(R + row) * 1024 + C0 + ln] = hb;
                long oi = ((long)(t * 32) + R + row) * 1024 + C0 + ln;  // ys (T,B,D)
                if (outbf) ((u16*)out)[oi] = hb;
                else       ((float*)out)[oi] = hn;
            }
        }
        if (t < 127) gbar2(leafs, gflag, 2 * t + 1, blk, NB);
    }
}

extern "C" void kernel_launch(void* const* d_in, const int* in_sizes, int n_in,
                              void* d_out, int out_size, void* d_ws, size_t ws_size,
                              hipStream_t stream)
{
    char* ws = (char*)d_ws;
    hipMemsetAsync(d_ws, 0, ZERO_BYTES, stream);   // leaves + flag + dtypes + h_bf16

    unsigned* leafs = (unsigned*)(ws + LEAF_OFF);
    unsigned* gflag = (unsigned*)(ws + FLAG_OFF);
    unsigned* flags = (unsigned*)(ws + FLG_OFF);
    u16*      hbf   = (u16*)(ws + HBF_OFF);
    u16*      rh    = (u16*)(ws + RH_OFF);
    float*    bs    = (float*)(ws + BS_OFF);
    u16*      xb    = (u16*)(ws + XB_OFF);

    Ptrs dp;
    for (int i = 0; i < 13; i++) dp.p[i] = d_in[i];
    detect_k<<<13, 256, 0, stream>>>(dp, flags);

    SPtrs sp;
    sp.x = d_in[0];
    sp.W[0] = d_in[1];  sp.W[1] = d_in[3];   // Wz, Uz
    sp.W[2] = d_in[5];  sp.W[3] = d_in[7];   // Wr, Ur
    sp.W[4] = d_in[9];  sp.W[5] = d_in[11];  // Wh, Uh
    sp.b[0] = d_in[2];  sp.b[1] = d_in[4];   // bz, cz
    sp.b[2] = d_in[6];  sp.b[3] = d_in[8];   // br, cr
    sp.b[4] = d_in[10]; sp.b[5] = d_in[12];  // bh, ch

    if (ws_size >= WS_FULL) {
        u16* wbuf = (u16*)(ws + WB_OFF);
        stage_k<<<2048 + 6 * 512 + 1, 256, 0, stream>>>(sp, flags, xb, wbuf, bs, 1);
        gru_rec<<<128, 1024, 0, stream>>>(xb, 1, wbuf, bs, hbf, rh, flags, leafs, gflag, d_out);
    } else {
        u16* wbuf = (u16*)(ws + XB_OFF);     // no x staging; weights at 1 MB
        stage_k<<<6 * 512 + 1, 256, 0, stream>>>(sp, flags, xb, wbuf, bs, 0);
        gru_rec<<<128, 1024, 0, stream>>>(d_in[0], 0, wbuf, bs, hbf, rh, flags, leafs, gflag, d_out);
    }
}

// Round 6
// 1926.516 us; speedup vs baseline: 12.3513x; 12.3513x over previous
//
#include <hip/hip_runtime.h>
#include <stdint.h>

// B=32, T=128, DIN=DOUT=1024. Input dtypes detected at runtime (bf16 vs fp32).
typedef unsigned short u16;
typedef unsigned long long u64;
typedef __attribute__((ext_vector_type(8))) short short8;   // 8 x bf16 MFMA operand
typedef __attribute__((ext_vector_type(4))) float f32x4;    // MFMA accumulator

// ---- workspace layout (bytes) ----
#define CNT_OFF    0                          // 256 epoch counters x 64 B
#define FLAGQ_OFF  16384                      // 256 epoch flags x 64 B
#define FLG_OFF    32768                      // 13 dtype flags
#define H64_OFF    36864                      // h bf16 as u64[32][256]: 64 KB (zeroed)
#define ZERO_BYTES (H64_OFF + 65536)
#define RH64_OFF   ZERO_BYTES                 // r*h bf16 u64[32][256]: 64 KB (wbr)
#define BS_OFF     (RH64_OFF + 65536)         // bias sums fp32: 3*1024*4
#define XB_OFF     (1<<20)                    // x bf16: 8 MB
#define WB_OFF     (9<<20)                    // 6 weight mats bf16: 12 MB
#define WS_FULL    (21u<<20)

__device__ __forceinline__ float bf2f(u16 v) {
    unsigned u = ((unsigned)v) << 16;
    return __builtin_bit_cast(float, u);
}
__device__ __forceinline__ u16 f2bf(float f) {
    unsigned u = __builtin_bit_cast(unsigned, f);
    unsigned r = 0x7fffu + ((u >> 16) & 1u);   // RNE
    return (u16)((u + r) >> 16);
}
__device__ __forceinline__ float sigm(float x) { return 1.0f / (1.0f + __expf(-x)); }

__device__ __forceinline__ short8 cvt8f(const float* f) {
    short8 r;
#pragma unroll
    for (int j = 0; j < 8; j++) r[j] = (short)f2bf(f[j]);
    return r;
}
__device__ __forceinline__ short8 cvt8any(const void* src, long ei, unsigned isbf) {
    if (isbf) return *(const short8*)((const u16*)src + ei);
    return cvt8f((const float*)src + ei);
}

union Q2 { u64 q[2]; short8 s; };
// Coherent (L2-bypassing, sc1) 16-byte fragment load as two relaxed agent atomics.
__device__ __forceinline__ short8 ld_coh8(const u64* p) {
    Q2 u;
    u.q[0] = __hip_atomic_load(p,     __ATOMIC_RELAXED, __HIP_MEMORY_SCOPE_AGENT);
    u.q[1] = __hip_atomic_load(p + 1, __ATOMIC_RELAXED, __HIP_MEMORY_SCOPE_AGENT);
    return u.s;
}

// ---- fence-free grid barrier ----
// NO __threadfence (agent fences = per-XCD L2 writeback+invalidate = the round-4/5
// disaster). Shared data travels via sc1 atomics (straight to L3), so ordering
// needs only: all stores drained (compiler's vmcnt(0) before s_barrier) ->
// leader RMW -> flag -> consumer loads (also sc1). Per-epoch counter+flag,
// monotone, zeroed once by memset.
__device__ __forceinline__ void gbar(unsigned* cnts, unsigned* flgs, unsigned e,
                                     int blk, unsigned nb) {
    __syncthreads();                 // drains vmcnt: all atomic stores are at L3
    if (threadIdx.x == 0) {
        unsigned* c = cnts + e * 16;
        unsigned* f = flgs + e * 16;
        __hip_atomic_fetch_add(c, 1u, __ATOMIC_RELAXED, __HIP_MEMORY_SCOPE_AGENT);
        if (blk == 0) {
            while (__hip_atomic_load(c, __ATOMIC_RELAXED, __HIP_MEMORY_SCOPE_AGENT) < nb)
                __builtin_amdgcn_s_sleep(1);
            __hip_atomic_store(f, 1u, __ATOMIC_RELAXED, __HIP_MEMORY_SCOPE_AGENT);
        } else {
            while (__hip_atomic_load(f, __ATOMIC_RELAXED, __HIP_MEMORY_SCOPE_AGENT) == 0)
                __builtin_amdgcn_s_sleep(2);
        }
    }
    __syncthreads();
}

struct Ptrs { const void* p[13]; };

// dtype detector: bf16 u16s have exponent in [100,140] (or zero) ~100% for
// N(0,s) data; fp32 read as u16 passes ~58%.
__global__ __launch_bounds__(256) void detect_k(Ptrs ps, unsigned* flags) {
    const u16* a = (const u16*)ps.p[blockIdx.x];
    __shared__ int tot;
    if (threadIdx.x == 0) tot = 0;
    __syncthreads();
    int cnt = 0;
    for (int i = threadIdx.x; i < 1024; i += 256) {
        unsigned u = a[i];
        unsigned e = (u >> 7) & 0xFF;
        cnt += (e == 0 || (e >= 100 && e <= 140)) ? 1 : 0;
    }
    atomicAdd(&tot, cnt);
    __syncthreads();
    if (threadIdx.x == 0) flags[blockIdx.x] = (tot >= 920) ? 1u : 0u;
}

struct SPtrs { const void* x; const void* W[6]; const void* b[6]; };
// W order: Wz,Uz,Wr,Ur,Wh,Uh (flags 1,3,5,7,9,11); b pairs (bz,cz),(br,cr),(bh,ch).

__global__ __launch_bounds__(256) void stage_k(SPtrs ps, const unsigned* __restrict__ flags,
                                               u16* __restrict__ xb, u16* __restrict__ wb,
                                               float* __restrict__ bs, int do_x) {
    int blk = blockIdx.x, tid = threadIdx.x;
    int xblocks = do_x ? 2048 : 0;
    if (blk < xblocks) {                         // x: 4M elems
        long ei = ((long)blk * 256 + tid) * 8;
        *(short8*)(xb + ei) = cvt8any(ps.x, ei, flags[0]);
    } else if (blk < xblocks + 6 * 512) {        // weights: 1M elems each
        int r = (blk - xblocks) >> 9;
        const int fidx[6] = {1, 3, 5, 7, 9, 11};
        long ei = ((long)((blk - xblocks) & 511) * 256 + tid) * 8;
        *(short8*)(wb + (long)r * 1048576 + ei) = cvt8any(ps.W[r], ei, flags[fidx[r]]);
    } else {                                     // bias sums: bs[0]=z, [1]=r, [2]=h
        const int fb[3] = {2, 6, 10}, fc[3] = {4, 8, 12};
        for (int g = 0; g < 3; g++)
            for (int i = tid; i < 1024; i += 256) {
                float b = flags[fb[g]] ? bf2f(((const u16*)ps.b[2 * g])[i])
                                       : ((const float*)ps.b[2 * g])[i];
                float c = flags[fc[g]] ? bf2f(((const u16*)ps.b[2 * g + 1])[i])
                                       : ((const float*)ps.b[2 * g + 1])[i];
                bs[g * 1024 + i] = b + c;
            }
    }
}

// ---- persistent GRU: 128 blocks x 1024 thr (16 waves), K-split chains ----
// Block (ct=blk>>1, rt=blk&1) owns rows R=[16rt,+16) (batch), cols C=[16ct,+16).
// h and r*h live as u64[32][256] (4 bf16 per u64), accessed ONLY via sc1
// atomics (L3 coherence point) -> weights stay L2-resident across all steps.
__global__ __launch_bounds__(1024, 4) void gru_rec(
    const void* __restrict__ xbase, int xmode,   // 1: xbase bf16-staged; 0: raw x
    const u16* __restrict__ wb, const float* __restrict__ bs,
    u64* __restrict__ h64, u64* __restrict__ rh64,
    const unsigned* __restrict__ flags,
    unsigned* __restrict__ cnts, unsigned* __restrict__ flgs,
    void* __restrict__ out)
{
    const int tid  = threadIdx.x;
    const int lane = tid & 63, wave = tid >> 6;      // wave 0..15
    const int quad = lane >> 4, ln = lane & 15;
    const int blk  = blockIdx.x;
    const unsigned NB = gridDim.x;

    const unsigned xisbf = xmode ? 1u : flags[0];
    const unsigned outbf = flags[0];

    const int ct = blk >> 1, rt = blk & 1;
    const int R = rt * 16, C0 = ct * 16;

    // Phase A role: g = wave>>2 (0:hUr 1:xWr 2:hUz 3:xWz), kq = wave&3.
    const int gA  = wave >> 2, kqA = wave & 3;
    const int kb0 = kqA * 256;
    const int wmapA[4] = {3, 2, 1, 0};               // -> Ur, Wr, Uz, Wz
    const u16* BwA = wb + (long)wmapA[gA] * 1048576 + (C0 + ln) * 1024 + kb0 + quad * 8;
    const bool hA  = (gA == 0) || (gA == 2);
    const u64* hAq = h64 + (R + ln) * 256 + (kb0 >> 2) + quad * 2;   // iter i: +i*8
    const long xAo = ((long)(R + ln) * 128) * 1024 + kb0 + quad * 8; // + t*1024

    // Phase B role: gB = wave>>3 (0:rh@Uh 1:x@Wh), ke = wave&7.
    const int gB  = wave >> 3, keB = wave & 7;
    const int kb1 = keB * 128;
    const u16* BwB = wb + (long)(gB ? 4 : 5) * 1048576 + (C0 + ln) * 1024 + kb1 + quad * 8;
    const u64* rhq = rh64 + (R + ln) * 256 + (kb1 >> 2) + quad * 2;  // iter i: +i*8
    const long xBo = ((long)(R + ln) * 128) * 1024 + kb1 + quad * 8; // + t*1024

    const float bias_z = bs[C0 + ln];
    const float bias_r = bs[1024 + C0 + ln];
    const float bias_h = bs[2048 + C0 + ln];

    __shared__ float sA[16][4][64];    // per-wave partials, conflict-free layout
    __shared__ float zt[4][64];        // z tile
    __shared__ float ht[4][64];        // h fp32 tile (block-private)
    __shared__ u16   tT[16][20];       // transpose staging for u64 packing

    if (wave == 0)
#pragma unroll
        for (int r = 0; r < 4; r++) ht[r][lane] = 0.f;
    __syncthreads();

    const int prow = lane >> 2, pseg = lane & 3;     // packer geometry (wave 0)

    for (int t = 0; t < 128; t++) {
        { // ---- phase A chains: 8 MFMAs ----
            f32x4 acc = (f32x4){0.f, 0.f, 0.f, 0.f};
            const long xo = xAo + (long)t * 1024;
#pragma unroll
            for (int i = 0; i < 8; i++) {
                short8 a = hA ? ld_coh8(hAq + i * 8)
                              : cvt8any(xbase, xo + i * 32, xisbf);
                acc = __builtin_amdgcn_mfma_f32_16x16x32_bf16(
                    a, *(const short8*)(BwA + i * 32), acc, 0, 0, 0);
            }
#pragma unroll
            for (int r = 0; r < 4; r++) sA[wave][r][lane] = acc[r];
        }
        __syncthreads();
        if (wave == 0) {        // r -> r*h, transpose via LDS, publish as u64 sc1
#pragma unroll
            for (int r = 0; r < 4; r++) {
                float s = bias_r;
#pragma unroll
                for (int w = 0; w < 8; w++) s += sA[w][r][lane];
                float rv = sigm(s);
                tT[quad * 4 + r][ln] = f2bf(rv * ht[r][lane]);
            }
            u64 v = (u64)tT[prow][pseg * 4] | ((u64)tT[prow][pseg * 4 + 1] << 16)
                  | ((u64)tT[prow][pseg * 4 + 2] << 32) | ((u64)tT[prow][pseg * 4 + 3] << 48);
            __hip_atomic_store(&rh64[(R + prow) * 256 + ct * 4 + pseg], v,
                               __ATOMIC_RELAXED, __HIP_MEMORY_SCOPE_AGENT);
        } else if (wave == 1) { // z -> LDS
#pragma unroll
            for (int r = 0; r < 4; r++) {
                float s = bias_z;
#pragma unroll
                for (int w = 8; w < 16; w++) s += sA[w][r][lane];
                zt[r][lane] = sigm(s);
            }
        }
        gbar(cnts, flgs, 2 * t, blk, NB);
        { // ---- phase B chains: 4 MFMAs ----
            f32x4 acc = (f32x4){0.f, 0.f, 0.f, 0.f};
            const long xo = xBo + (long)t * 1024;
#pragma unroll
            for (int i = 0; i < 4; i++) {
                short8 a = (gB == 0) ? ld_coh8(rhq + i * 8)
                                     : cvt8any(xbase, xo + i * 32, xisbf);
                acc = __builtin_amdgcn_mfma_f32_16x16x32_bf16(
                    a, *(const short8*)(BwB + i * 32), acc, 0, 0, 0);
            }
#pragma unroll
            for (int r = 0; r < 4; r++) sA[wave][r][lane] = acc[r];
        }
        __syncthreads();
        if (wave == 0) {        // combine: h' = (1-z)h + z*sigm(.), publish h
#pragma unroll
            for (int r = 0; r < 4; r++) {
                float s = bias_h;
#pragma unroll
                for (int w = 0; w < 16; w++) s += sA[w][r][lane];
                float hh = sigm(s);
                float z  = zt[r][lane];
                float hv = ht[r][lane];
                float hn = (1.0f - z) * hv + z * hh;
                ht[r][lane] = hn;
                u16 hb = f2bf(hn);
                int row = quad * 4 + r;
                tT[row][ln] = hb;
                long oi = ((long)(t * 32) + R + row) * 1024 + C0 + ln;  // ys (T,B,D)
                if (outbf) ((u16*)out)[oi] = hb;
                else       ((float*)out)[oi] = hn;
            }
            u64 v = (u64)tT[prow][pseg * 4] | ((u64)tT[prow][pseg * 4 + 1] << 16)
                  | ((u64)tT[prow][pseg * 4 + 2] << 32) | ((u64)tT[prow][pseg * 4 + 3] << 48);
            __hip_atomic_store(&h64[(R + prow) * 256 + ct * 4 + pseg], v,
                               __ATOMIC_RELAXED, __HIP_MEMORY_SCOPE_AGENT);
        }
        if (t < 127) gbar(cnts, flgs, 2 * t + 1, blk, NB);
    }
}

extern "C" void kernel_launch(void* const* d_in, const int* in_sizes, int n_in,
                              void* d_out, int out_size, void* d_ws, size_t ws_size,
                              hipStream_t stream)
{
    char* ws = (char*)d_ws;
    hipMemsetAsync(d_ws, 0, ZERO_BYTES, stream);   // counters + flags + dtypes + h64

    unsigned* cnts  = (unsigned*)(ws + CNT_OFF);
    unsigned* flgs  = (unsigned*)(ws + FLAGQ_OFF);
    unsigned* flags = (unsigned*)(ws + FLG_OFF);
    u64*      h64   = (u64*)(ws + H64_OFF);
    u64*      rh64  = (u64*)(ws + RH64_OFF);
    float*    bs    = (float*)(ws + BS_OFF);
    u16*      xb    = (u16*)(ws + XB_OFF);

    Ptrs dp;
    for (int i = 0; i < 13; i++) dp.p[i] = d_in[i];
    detect_k<<<13, 256, 0, stream>>>(dp, flags);

    SPtrs sp;
    sp.x = d_in[0];
    sp.W[0] = d_in[1];  sp.W[1] = d_in[3];   // Wz, Uz
    sp.W[2] = d_in[5];  sp.W[3] = d_in[7];   // Wr, Ur
    sp.W[4] = d_in[9];  sp.W[5] = d_in[11];  // Wh, Uh
    sp.b[0] = d_in[2];  sp.b[1] = d_in[4];   // bz, cz
    sp.b[2] = d_in[6];  sp.b[3] = d_in[8];   // br, cr
    sp.b[4] = d_in[10]; sp.b[5] = d_in[12];  // bh, ch

    if (ws_size >= WS_FULL) {
        u16* wbuf = (u16*)(ws + WB_OFF);
        stage_k<<<2048 + 6 * 512 + 1, 256, 0, stream>>>(sp, flags, xb, wbuf, bs, 1);
        gru_rec<<<128, 1024, 0, stream>>>(xb, 1, wbuf, bs, h64, rh64, flags, cnts, flgs, d_out);
    } else {
        u16* wbuf = (u16*)(ws + XB_OFF);     // no x staging; weights at 1 MB
        stage_k<<<6 * 512 + 1, 256, 0, stream>>>(sp, flags, xb, wbuf, bs, 0);
        gru_rec<<<128, 1024, 0, stream>>>(d_in[0], 0, wbuf, bs, h64, rh64, flags, cnts, flgs, d_out);
    }
}